// Round 1
// baseline (263.818 us; speedup 1.0000x reference)
//
#include <hip/hip_runtime.h>
#include <stdint.h>

#define Bn 64
#define Sn 512
#define SPn 520
#define Dn 768
#define Fn 256
#define BT 256
#define BF 128

typedef short bf16x8 __attribute__((ext_vector_type(8)));
typedef float f32x4 __attribute__((ext_vector_type(4)));

static __device__ __forceinline__ unsigned short f2bf(float f) {
  union { float f; unsigned u; } v; v.f = f;
  unsigned r = v.u + 0x7FFFu + ((v.u >> 16) & 1u);
  return (unsigned short)(r >> 16);
}

// ---------------------------------------------------------------------------
// 1) stable compaction + f32->bf16: hc[b][t][d], rows t>=L zeroed, 8 pad rows
// ---------------------------------------------------------------------------
__global__ __launch_bounds__(256) void compact_kernel(
    const int* __restrict__ x, const float* __restrict__ h,
    unsigned short* __restrict__ hc, int* __restrict__ Lout) {
  int b = blockIdx.x, rblk = blockIdx.y;
  __shared__ unsigned long long masks[8];
  __shared__ short sidx[Sn];
  int tid = threadIdx.x, lane = tid & 63, wv = tid >> 6;
  for (int c = wv; c < 8; c += 4) {
    bool pred = x[b * Sn + c * 64 + lane] != 0;
    unsigned long long m = __ballot(pred);
    if (lane == 0) masks[c] = m;
  }
  __syncthreads();
  int pref[9]; pref[0] = 0;
  #pragma unroll
  for (int c = 0; c < 8; ++c) pref[c + 1] = pref[c] + __popcll(masks[c]);
  int L = pref[8];
  for (int p = tid; p < Sn; p += 256) {
    int c = p >> 6, l = p & 63;
    unsigned long long m = masks[c];
    if ((m >> l) & 1ull)
      sidx[pref[c] + __popcll(m & ((1ull << l) - 1ull))] = (short)p;
  }
  if (rblk == 0 && tid == 0) Lout[b] = L;
  __syncthreads();
  int r0 = rblk * 65;  // 8 * 65 = 520 rows
  for (int r = r0 + wv; r < r0 + 65; r += 4) {
    unsigned short* dst = hc + ((size_t)b * SPn + r) * Dn;
    if (r < L) {
      const float* src = h + ((size_t)b * Sn + sidx[r]) * Dn;
      #pragma unroll
      for (int c = 0; c < 3; ++c) {
        int d = c * 256 + lane * 4;
        float4 v = *(const float4*)(src + d);
        ushort4 o = { f2bf(v.x), f2bf(v.y), f2bf(v.z), f2bf(v.w) };
        *(ushort4*)(dst + d) = o;
      }
    } else {
      ushort4 z = {0, 0, 0, 0};
      #pragma unroll
      for (int c = 0; c < 3; ++c) *(ushort4*)(dst + c * 256 + lane * 4) = z;
    }
  }
}

// ---------------------------------------------------------------------------
// 2) weight repack: Wp[m][d] bf16, m = brOff + j*256 + f  (d innermost)
// ---------------------------------------------------------------------------
__global__ __launch_bounds__(128) void wpack_kernel(
    const float* __restrict__ w2, const float* __restrict__ w3,
    const float* __restrict__ w4, const float* __restrict__ w5,
    unsigned short* __restrict__ Wp) {
  int m = blockIdx.x;
  const float* w; int k, r;
  if (m < 512)       { w = w2; k = 2; r = m; }
  else if (m < 1280) { w = w3; k = 3; r = m - 512; }
  else if (m < 2304) { w = w4; k = 4; r = m - 1280; }
  else               { w = w5; k = 5; r = m - 2304; }
  int j = r >> 8, f = r & 255;
  const float* src = w + (size_t)f * Dn * k + j;   // w[f][d][j], stride k over d
  unsigned short* dst = Wp + (size_t)m * Dn;
  for (int d = threadIdx.x; d < Dn; d += 128) dst[d] = f2bf(src[(size_t)d * k]);
}

// ---------------------------------------------------------------------------
// 3) fused conv-GEMM (t in M, f in N) + bias + mask + relu + max-pool atomic
//    tile: 256t x 128f, 4 waves (each 64t x 128f), BK=32, XOR-swizzled LDS
// ---------------------------------------------------------------------------
__global__ __launch_bounds__(256, 2) void conv_kernel(
    const unsigned short* __restrict__ hc, const unsigned short* __restrict__ Wp,
    const float* __restrict__ b2, const float* __restrict__ b3,
    const float* __restrict__ b4, const float* __restrict__ b5,
    const int* __restrict__ Lptr, int* __restrict__ feats) {
  __shared__ char smem[(BT + 4 + 5 * BF) * 64];   // 57600 B: A=260 rows, B=k*128 rows
  int idx = blockIdx.x;
  int b = idx & 63, tt = (idx >> 6) & 1, ff = (idx >> 7) & 1, br = idx >> 8;
  int kk = br + 2;
  int mBase = 256 * ((br * (br + 3)) >> 1) + ff * BF;  // 0,512,1280,2304 (+ff*128)
  const float* bias = (br == 0) ? b2 : (br == 1) ? b3 : (br == 2) ? b4 : b5;
  int Lb = Lptr[b];
  int tid = threadIdx.x, lane = tid & 63, wv = tid >> 6;
  char* sA = smem;
  char* sB = smem + (BT + 4) * 64;
  int t_base = tt * BT;
  f32x4 acc[4][8];
  #pragma unroll
  for (int m = 0; m < 4; ++m)
    #pragma unroll
    for (int n = 0; n < 8; ++n) acc[m][n] = (f32x4)0.f;

  const unsigned short* hcB = hc + ((size_t)b * SPn + t_base) * Dn;
  int lrow = lane & 15, lg = lane >> 4;

  for (int d0 = 0; d0 < Dn; d0 += 32) {
    // stage A: 260 rows x 32 d (64B/row), swizzle seg ^ ((row>>1)&3)
    for (int s = tid; s < (BT + 4) * 4; s += 256) {
      int row = s >> 2, seg = s & 3;
      bf16x8 v = *(const bf16x8*)(hcB + (size_t)row * Dn + d0 + seg * 8);
      *(bf16x8*)(sA + row * 64 + ((seg ^ ((row >> 1) & 3)) << 4)) = v;
    }
    // stage B: kk*128 weight rows x 32 d
    for (int s = tid; s < kk * BF * 4; s += 256) {
      int row = s >> 2, seg = s & 3;
      int j = row >> 7, fr = row & 127;
      bf16x8 v = *(const bf16x8*)(Wp + (size_t)(mBase + j * Fn + fr) * Dn + d0 + seg * 8);
      *(bf16x8*)(sB + row * 64 + ((seg ^ ((row >> 1) & 3)) << 4)) = v;
    }
    __syncthreads();
    for (int j = 0; j < kk; ++j) {
      bf16x8 Bf[8];
      #pragma unroll
      for (int n = 0; n < 8; ++n) {
        int row = j * BF + n * 16 + lrow;
        Bf[n] = *(const bf16x8*)(sB + row * 64 + ((lg ^ ((row >> 1) & 3)) << 4));
      }
      #pragma unroll
      for (int m = 0; m < 4; ++m) {
        int row = wv * 64 + m * 16 + lrow + j;   // shifted A read = the conv shift
        bf16x8 Af = *(const bf16x8*)(sA + row * 64 + ((lg ^ ((row >> 1) & 3)) << 4));
        #pragma unroll
        for (int n = 0; n < 8; ++n)
          acc[m][n] = __builtin_amdgcn_mfma_f32_16x16x32_bf16(Af, Bf[n], acc[m][n], 0, 0, 0);
      }
    }
    __syncthreads();
  }
  // epilogue: bias + validity mask + relu + max over t, then atomicMax
  int validLim = Lb - kk + 1;
  #pragma unroll
  for (int n = 0; n < 8; ++n) {
    int fg = ff * BF + n * 16 + lrow;            // f within branch [0,256)
    float bv = bias[fg];
    float pmax = 0.f;
    #pragma unroll
    for (int m = 0; m < 4; ++m)
      #pragma unroll
      for (int i = 0; i < 4; ++i) {
        int t = t_base + wv * 64 + m * 16 + lg * 4 + i;
        float v = acc[m][n][i] + bv;
        pmax = fmaxf(pmax, (t < validLim) ? fmaxf(v, 0.f) : 0.f);
      }
    pmax = fmaxf(pmax, __shfl_xor(pmax, 16));
    pmax = fmaxf(pmax, __shfl_xor(pmax, 32));
    if (lane < 16)
      atomicMax(feats + b * 1024 + br * 256 + fg, __float_as_int(pmax));
  }
}

// ---------------------------------------------------------------------------
// 4) FC + sigmoid
// ---------------------------------------------------------------------------
__global__ __launch_bounds__(64) void fc_kernel(
    const int* __restrict__ feats, const float* __restrict__ fcw,
    const float* __restrict__ fcb, float* __restrict__ out) {
  int b = blockIdx.x, lane = threadIdx.x;
  float acc = 0.f;
  for (int i = lane; i < 1024; i += 64)
    acc += __int_as_float(feats[b * 1024 + i]) * fcw[i];
  #pragma unroll
  for (int off = 32; off; off >>= 1) acc += __shfl_xor(acc, off);
  if (lane == 0) out[b] = 1.f / (1.f + expf(-(acc + fcb[0])));
}

extern "C" void kernel_launch(void* const* d_in, const int* in_sizes, int n_in,
                              void* d_out, int out_size, void* d_ws, size_t ws_size,
                              hipStream_t stream) {
  const int*   x   = (const int*)d_in[0];
  const float* h   = (const float*)d_in[1];
  const float* w2  = (const float*)d_in[2];
  const float* b2  = (const float*)d_in[3];
  const float* w3  = (const float*)d_in[4];
  const float* b3  = (const float*)d_in[5];
  const float* w4  = (const float*)d_in[6];
  const float* b4  = (const float*)d_in[7];
  const float* w5  = (const float*)d_in[8];
  const float* b5  = (const float*)d_in[9];
  const float* fcw = (const float*)d_in[10];
  const float* fcb = (const float*)d_in[11];
  float* out = (float*)d_out;
  char* ws = (char*)d_ws;
  unsigned short* hc = (unsigned short*)ws;               // 64*520*768*2 = 51,118,080
  unsigned short* Wp = (unsigned short*)(ws + 51118080);  // 3584*768*2   =  5,505,024
  int* feats = (int*)(ws + 56623104);                     // 64*1024*4    =    262,144
  int* Lbuf  = (int*)(ws + 56885248);                     // 64*4

  hipMemsetAsync(feats, 0, 64 * 1024 * 4, stream);        // zero bits == 0.0f == relu floor
  compact_kernel<<<dim3(64, 8), 256, 0, stream>>>(x, h, hc, Lbuf);
  wpack_kernel<<<3584, 128, 0, stream>>>(w2, w3, w4, w5, Wp);
  conv_kernel<<<1024, 256, 0, stream>>>(hc, Wp, b2, b3, b4, b5, Lbuf, feats);
  fc_kernel<<<64, 64, 0, stream>>>(feats, fcw, fcb, out);
}

// Round 2
// 251.469 us; speedup vs baseline: 1.0491x; 1.0491x over previous
//
#include <hip/hip_runtime.h>
#include <stdint.h>

#define Bn 64
#define Sn 512
#define SPn 520
#define Dn 768
#define Fn 256
#define BT 256
#define BF 128

typedef short bf16x8 __attribute__((ext_vector_type(8)));
typedef float f32x4 __attribute__((ext_vector_type(4)));

static __device__ __forceinline__ unsigned short f2bf(float f) {
  union { float f; unsigned u; } v; v.f = f;
  unsigned r = v.u + 0x7FFFu + ((v.u >> 16) & 1u);
  return (unsigned short)(r >> 16);
}

// ---------------------------------------------------------------------------
// 1) stable compaction + f32->bf16: hc[b][t][d], rows t>=L zeroed, 8 pad rows
// ---------------------------------------------------------------------------
__global__ __launch_bounds__(256) void compact_kernel(
    const int* __restrict__ x, const float* __restrict__ h,
    unsigned short* __restrict__ hc, int* __restrict__ Lout) {
  int b = blockIdx.x, rblk = blockIdx.y;
  __shared__ unsigned long long masks[8];
  __shared__ short sidx[Sn];
  int tid = threadIdx.x, lane = tid & 63, wv = tid >> 6;
  for (int c = wv; c < 8; c += 4) {
    bool pred = x[b * Sn + c * 64 + lane] != 0;
    unsigned long long m = __ballot(pred);
    if (lane == 0) masks[c] = m;
  }
  __syncthreads();
  int pref[9]; pref[0] = 0;
  #pragma unroll
  for (int c = 0; c < 8; ++c) pref[c + 1] = pref[c] + __popcll(masks[c]);
  int L = pref[8];
  for (int p = tid; p < Sn; p += 256) {
    int c = p >> 6, l = p & 63;
    unsigned long long m = masks[c];
    if ((m >> l) & 1ull)
      sidx[pref[c] + __popcll(m & ((1ull << l) - 1ull))] = (short)p;
  }
  if (rblk == 0 && tid == 0) Lout[b] = L;
  __syncthreads();
  int r0 = rblk * 65;  // 8 * 65 = 520 rows
  for (int r = r0 + wv; r < r0 + 65; r += 4) {
    unsigned short* dst = hc + ((size_t)b * SPn + r) * Dn;
    if (r < L) {
      const float* src = h + ((size_t)b * Sn + sidx[r]) * Dn;
      #pragma unroll
      for (int c = 0; c < 3; ++c) {
        int d = c * 256 + lane * 4;
        float4 v = *(const float4*)(src + d);
        ushort4 o = { f2bf(v.x), f2bf(v.y), f2bf(v.z), f2bf(v.w) };
        *(ushort4*)(dst + d) = o;
      }
    } else {
      ushort4 z = {0, 0, 0, 0};
      #pragma unroll
      for (int c = 0; c < 3; ++c) *(ushort4*)(dst + c * 256 + lane * 4) = z;
    }
  }
}

// ---------------------------------------------------------------------------
// 2) weight repack: Wp[m][d] bf16, m = brOff + j*256 + f  (d innermost)
// ---------------------------------------------------------------------------
__global__ __launch_bounds__(128) void wpack_kernel(
    const float* __restrict__ w2, const float* __restrict__ w3,
    const float* __restrict__ w4, const float* __restrict__ w5,
    unsigned short* __restrict__ Wp) {
  int m = blockIdx.x;
  const float* w; int k, r;
  if (m < 512)       { w = w2; k = 2; r = m; }
  else if (m < 1280) { w = w3; k = 3; r = m - 512; }
  else if (m < 2304) { w = w4; k = 4; r = m - 1280; }
  else               { w = w5; k = 5; r = m - 2304; }
  int j = r >> 8, f = r & 255;
  const float* src = w + (size_t)f * Dn * k + j;   // w[f][d][j], stride k over d
  unsigned short* dst = Wp + (size_t)m * Dn;
  for (int d = threadIdx.x; d < Dn; d += 128) dst[d] = f2bf(src[(size_t)d * k]);
}

// ---------------------------------------------------------------------------
// 3) fused conv-GEMM (t in M, f in N) + bias + mask + relu + max-pool atomic
//    tile: 256t x 128f, 4 waves (each 64t x 128f), BK=32, XOR-swizzled LDS
//    Work-skip: whole-block exit if tile fully invalid; wave-uniform per-m
//    fragment skip at 16-row granularity; A-stage rows trimmed to valid+halo.
// ---------------------------------------------------------------------------
__global__ __launch_bounds__(256, 2) void conv_kernel(
    const unsigned short* __restrict__ hc, const unsigned short* __restrict__ Wp,
    const float* __restrict__ b2, const float* __restrict__ b3,
    const float* __restrict__ b4, const float* __restrict__ b5,
    const int* __restrict__ Lptr, int* __restrict__ feats) {
  __shared__ char smem[(BT + 4 + 5 * BF) * 64];   // 57600 B: A=260 rows, B=k*128 rows
  int idx = blockIdx.x;
  int b = idx & 63, tt = (idx >> 6) & 1, ff = (idx >> 7) & 1, br = idx >> 8;
  int kk = br + 2;
  int mBase = 256 * ((br * (br + 3)) >> 1) + ff * BF;  // 0,512,1280,2304 (+ff*128)
  const float* bias = (br == 0) ? b2 : (br == 1) ? b3 : (br == 2) ? b4 : b5;
  int Lb = Lptr[b];
  int t_base = tt * BT;
  int validLim = Lb - kk + 1;          // conv position t valid iff t < validLim
  int VT = validLim - t_base;          // valid t-count within this tile
  if (VT <= 0) return;                 // block-uniform: whole tile invalid
  int RA = min(BT + 4, VT + 20);       // A rows needed: fragments read < VT+19

  int tid = threadIdx.x, lane = tid & 63, wv = tid >> 6;
  char* sA = smem;
  char* sB = smem + (BT + 4) * 64;
  bool waveActive = (wv * 64 < VT);    // wave-uniform
  f32x4 acc[4][8];
  #pragma unroll
  for (int m = 0; m < 4; ++m)
    #pragma unroll
    for (int n = 0; n < 8; ++n) acc[m][n] = (f32x4)0.f;

  const unsigned short* hcB = hc + ((size_t)b * SPn + t_base) * Dn;
  int lrow = lane & 15, lg = lane >> 4;

  for (int d0 = 0; d0 < Dn; d0 += 32) {
    // stage A: RA rows x 32 d (64B/row), swizzle seg ^ ((row>>1)&3)
    for (int s = tid; s < RA * 4; s += 256) {
      int row = s >> 2, seg = s & 3;
      bf16x8 v = *(const bf16x8*)(hcB + (size_t)row * Dn + d0 + seg * 8);
      *(bf16x8*)(sA + row * 64 + ((seg ^ ((row >> 1) & 3)) << 4)) = v;
    }
    // stage B: kk*128 weight rows x 32 d
    for (int s = tid; s < kk * BF * 4; s += 256) {
      int row = s >> 2, seg = s & 3;
      int j = row >> 7, fr = row & 127;
      bf16x8 v = *(const bf16x8*)(Wp + (size_t)(mBase + j * Fn + fr) * Dn + d0 + seg * 8);
      *(bf16x8*)(sB + row * 64 + ((seg ^ ((row >> 1) & 3)) << 4)) = v;
    }
    __syncthreads();
    if (waveActive) {
      for (int j = 0; j < kk; ++j) {
        bf16x8 Bf[8];
        #pragma unroll
        for (int n = 0; n < 8; ++n) {
          int row = j * BF + n * 16 + lrow;
          Bf[n] = *(const bf16x8*)(sB + row * 64 + ((lg ^ ((row >> 1) & 3)) << 4));
        }
        #pragma unroll
        for (int m = 0; m < 4; ++m) {
          if (wv * 64 + m * 16 < VT) {             // wave-uniform fragment skip
            int row = wv * 64 + m * 16 + lrow + j; // shifted A read = the conv shift
            bf16x8 Af = *(const bf16x8*)(sA + row * 64 + ((lg ^ ((row >> 1) & 3)) << 4));
            #pragma unroll
            for (int n = 0; n < 8; ++n)
              acc[m][n] = __builtin_amdgcn_mfma_f32_16x16x32_bf16(Af, Bf[n], acc[m][n], 0, 0, 0);
          }
        }
      }
    }
    __syncthreads();
  }
  if (!waveActive) return;             // after last barrier: safe to exit
  // epilogue: bias + validity mask + relu + max over t, then atomicMax
  #pragma unroll
  for (int n = 0; n < 8; ++n) {
    int fg = ff * BF + n * 16 + lrow;            // f within branch [0,256)
    float bv = bias[fg];
    float pmax = 0.f;
    #pragma unroll
    for (int m = 0; m < 4; ++m)
      #pragma unroll
      for (int i = 0; i < 4; ++i) {
        int t = t_base + wv * 64 + m * 16 + lg * 4 + i;
        float v = acc[m][n][i] + bv;
        pmax = fmaxf(pmax, (t < validLim) ? fmaxf(v, 0.f) : 0.f);
      }
    pmax = fmaxf(pmax, __shfl_xor(pmax, 16));
    pmax = fmaxf(pmax, __shfl_xor(pmax, 32));
    if (lane < 16)
      atomicMax(feats + b * 1024 + br * 256 + fg, __float_as_int(pmax));
  }
}

// ---------------------------------------------------------------------------
// 4) FC + sigmoid
// ---------------------------------------------------------------------------
__global__ __launch_bounds__(64) void fc_kernel(
    const int* __restrict__ feats, const float* __restrict__ fcw,
    const float* __restrict__ fcb, float* __restrict__ out) {
  int b = blockIdx.x, lane = threadIdx.x;
  float acc = 0.f;
  for (int i = lane; i < 1024; i += 64)
    acc += __int_as_float(feats[b * 1024 + i]) * fcw[i];
  #pragma unroll
  for (int off = 32; off; off >>= 1) acc += __shfl_xor(acc, off);
  if (lane == 0) out[b] = 1.f / (1.f + expf(-(acc + fcb[0])));
}

extern "C" void kernel_launch(void* const* d_in, const int* in_sizes, int n_in,
                              void* d_out, int out_size, void* d_ws, size_t ws_size,
                              hipStream_t stream) {
  const int*   x   = (const int*)d_in[0];
  const float* h   = (const float*)d_in[1];
  const float* w2  = (const float*)d_in[2];
  const float* b2  = (const float*)d_in[3];
  const float* w3  = (const float*)d_in[4];
  const float* b3  = (const float*)d_in[5];
  const float* w4  = (const float*)d_in[6];
  const float* b4  = (const float*)d_in[7];
  const float* w5  = (const float*)d_in[8];
  const float* b5  = (const float*)d_in[9];
  const float* fcw = (const float*)d_in[10];
  const float* fcb = (const float*)d_in[11];
  float* out = (float*)d_out;
  char* ws = (char*)d_ws;
  unsigned short* hc = (unsigned short*)ws;               // 64*520*768*2 = 51,118,080
  unsigned short* Wp = (unsigned short*)(ws + 51118080);  // 3584*768*2   =  5,505,024
  int* feats = (int*)(ws + 56623104);                     // 64*1024*4    =    262,144
  int* Lbuf  = (int*)(ws + 56885248);                     // 64*4

  hipMemsetAsync(feats, 0, 64 * 1024 * 4, stream);        // zero bits == 0.0f == relu floor
  compact_kernel<<<dim3(64, 8), 256, 0, stream>>>(x, h, hc, Lbuf);
  wpack_kernel<<<3584, 128, 0, stream>>>(w2, w3, w4, w5, Wp);
  conv_kernel<<<1024, 256, 0, stream>>>(hc, Wp, b2, b3, b4, b5, Lbuf, feats);
  fc_kernel<<<64, 64, 0, stream>>>(feats, fcw, fcb, out);
}

// Round 3
// 248.006 us; speedup vs baseline: 1.0638x; 1.0140x over previous
//
#include <hip/hip_runtime.h>
#include <stdint.h>

#define Bn 64
#define Sn 512
#define SPn 520
#define Dn 768
#define Fn 256

typedef short bf16x8 __attribute__((ext_vector_type(8)));
typedef float f32x4 __attribute__((ext_vector_type(4)));

static __device__ __forceinline__ unsigned short f2bf(float f) {
  union { float f; unsigned u; } v; v.f = f;
  unsigned r = v.u + 0x7FFFu + ((v.u >> 16) & 1u);
  return (unsigned short)(r >> 16);
}

// ---------------------------------------------------------------------------
// 1) stable compaction + f32->bf16: hc[b][t][d], rows t>=L zeroed, 8 pad rows
// ---------------------------------------------------------------------------
__global__ __launch_bounds__(256) void compact_kernel(
    const int* __restrict__ x, const float* __restrict__ h,
    unsigned short* __restrict__ hc, int* __restrict__ Lout) {
  int b = blockIdx.x, rblk = blockIdx.y;
  __shared__ unsigned long long masks[8];
  __shared__ short sidx[Sn];
  int tid = threadIdx.x, lane = tid & 63, wv = tid >> 6;
  for (int c = wv; c < 8; c += 4) {
    bool pred = x[b * Sn + c * 64 + lane] != 0;
    unsigned long long m = __ballot(pred);
    if (lane == 0) masks[c] = m;
  }
  __syncthreads();
  int pref[9]; pref[0] = 0;
  #pragma unroll
  for (int c = 0; c < 8; ++c) pref[c + 1] = pref[c] + __popcll(masks[c]);
  int L = pref[8];
  for (int p = tid; p < Sn; p += 256) {
    int c = p >> 6, l = p & 63;
    unsigned long long m = masks[c];
    if ((m >> l) & 1ull)
      sidx[pref[c] + __popcll(m & ((1ull << l) - 1ull))] = (short)p;
  }
  if (rblk == 0 && tid == 0) Lout[b] = L;
  __syncthreads();
  int r0 = rblk * 65;  // 8 * 65 = 520 rows
  for (int r = r0 + wv; r < r0 + 65; r += 4) {
    unsigned short* dst = hc + ((size_t)b * SPn + r) * Dn;
    if (r < L) {
      const float* src = h + ((size_t)b * Sn + sidx[r]) * Dn;
      #pragma unroll
      for (int c = 0; c < 3; ++c) {
        int d = c * 256 + lane * 4;
        float4 v = *(const float4*)(src + d);
        ushort4 o = { f2bf(v.x), f2bf(v.y), f2bf(v.z), f2bf(v.w) };
        *(ushort4*)(dst + d) = o;
      }
    } else {
      ushort4 z = {0, 0, 0, 0};
      #pragma unroll
      for (int c = 0; c < 3; ++c) *(ushort4*)(dst + c * 256 + lane * 4) = z;
    }
  }
}

// ---------------------------------------------------------------------------
// 1.5) plan: 16-aligned per-batch segments packed densely; rowmap[p]=(b,L,t)
// ---------------------------------------------------------------------------
__global__ __launch_bounds__(256) void plan_kernel(
    const int* __restrict__ Lbuf, int* __restrict__ plan, int* __restrict__ rowmap) {
  __shared__ int sOff[65];
  __shared__ int sL[64];
  int tid = threadIdx.x;
  if (tid < 64) {
    int L = Lbuf[tid];
    int SL = (L + 15) & ~15;
    int pre = SL;
    #pragma unroll
    for (int off = 1; off < 64; off <<= 1) {
      int y = __shfl_up(pre, off);
      if (tid >= off) pre += y;
    }
    sOff[tid] = pre - SL;           // exclusive prefix
    sL[tid] = L;
    if (tid == 63) { sOff[64] = pre; plan[0] = (pre + 255) >> 8; }
  }
  __syncthreads();
  int M = sOff[64];
  for (int b = 0; b < 64; ++b) {
    int off = sOff[b], L = sL[b];
    int SL = (L + 15) & ~15;
    int enc = (b << 20) | (L << 10);
    for (int t = tid; t < SL; t += 256) rowmap[off + t] = enc | t;
  }
  for (int p = M + tid; p < M + 260; p += 256)
    rowmap[p] = 512;                // sentinel: b=0, L=0, t=512 (zero pad row)
}

// ---------------------------------------------------------------------------
// 2) weight repack: Wp[m][d] bf16, m = brOff + j*256 + f  (d innermost)
// ---------------------------------------------------------------------------
__global__ __launch_bounds__(128) void wpack_kernel(
    const float* __restrict__ w2, const float* __restrict__ w3,
    const float* __restrict__ w4, const float* __restrict__ w5,
    unsigned short* __restrict__ Wp) {
  int m = blockIdx.x;
  const float* w; int k, r;
  if (m < 512)       { w = w2; k = 2; r = m; }
  else if (m < 1280) { w = w3; k = 3; r = m - 512; }
  else if (m < 2304) { w = w4; k = 4; r = m - 1280; }
  else               { w = w5; k = 5; r = m - 2304; }
  int j = r >> 8, f = r & 255;
  const float* src = w + (size_t)f * Dn * k + j;   // w[f][d][j], stride k over d
  unsigned short* dst = Wp + (size_t)m * Dn;
  for (int d = threadIdx.x; d < Dn; d += 128) dst[d] = f2bf(src[(size_t)d * k]);
}

// ---------------------------------------------------------------------------
// 3) packed-M conv-GEMM: dense tiles over concatenated valid rows.
//    tile = 256 packed rows x 128 f, 4 waves, BK=32, XOR-swizzled LDS.
//    Segments 16-aligned => each m-fragment belongs to exactly one batch.
// ---------------------------------------------------------------------------
__global__ __launch_bounds__(256, 2) void conv_kernel(
    const unsigned short* __restrict__ hc, const unsigned short* __restrict__ Wp,
    const float* __restrict__ b2, const float* __restrict__ b3,
    const float* __restrict__ b4, const float* __restrict__ b5,
    const int* __restrict__ plan, const int* __restrict__ rowmap,
    int* __restrict__ feats) {
  __shared__ char smem[(260 + 640) * 64];   // A: 260 rows, B: kk*128 rows (<=640)
  int idx = blockIdx.x;
  int tile = idx >> 3, sub = idx & 7;
  if (tile >= plan[0]) return;
  int br = sub >> 1, ff = sub & 1, kk = br + 2;
  int mBase = 256 * ((br * (br + 3)) >> 1) + ff * 128;  // 0,512,1280,2304 (+ff*128)
  const float* bias = (br == 0) ? b2 : (br == 1) ? b3 : (br == 2) ? b4 : b5;
  int tid = threadIdx.x, lane = tid & 63, wv = tid >> 6;
  int lrow = lane & 15, lg = lane >> 4;
  char* sA = smem;
  char* sB = smem + 260 * 64;
  int P0 = tile << 8;

  // A-staging sources are d0-invariant: resolve rowmap once, keep pointers.
  const unsigned short* srcA[5];
  int dstA[5];
  #pragma unroll
  for (int i = 0; i < 5; ++i) {
    if (i < 4 || tid < 16) {
      int s = tid + i * 256;                 // s < 1040 (260 rows x 4 segs)
      int row = s >> 2, seg = s & 3;
      int rm = rowmap[P0 + row];
      int bb = rm >> 20, t = rm & 1023;
      srcA[i] = hc + ((size_t)(bb * SPn + t)) * Dn + seg * 8;
      dstA[i] = row * 64 + ((seg ^ ((row >> 1) & 3)) << 4);
    }
  }
  const unsigned short* srcB[10];
  int dstB[10];
  int nB = kk * 2;                           // kk*128 rows x 4 segs / 256 thr
  #pragma unroll
  for (int i = 0; i < 10; ++i) {
    if (i < nB) {
      int s = tid + i * 256;
      int row = s >> 2, seg = s & 3;
      int j = row >> 7, fr = row & 127;
      srcB[i] = Wp + ((size_t)(mBase + j * Fn + fr)) * Dn + seg * 8;
      dstB[i] = row * 64 + ((seg ^ ((row >> 1) & 3)) << 4);
    }
  }

  f32x4 acc[4][8];
  #pragma unroll
  for (int m = 0; m < 4; ++m)
    #pragma unroll
    for (int n = 0; n < 8; ++n) acc[m][n] = (f32x4)0.f;

  for (int d0 = 0; d0 < Dn; d0 += 32) {
    #pragma unroll
    for (int i = 0; i < 5; ++i)
      if (i < 4 || tid < 16)
        *(bf16x8*)(sA + dstA[i]) = *(const bf16x8*)(srcA[i] + d0);
    #pragma unroll
    for (int i = 0; i < 10; ++i)
      if (i < nB)
        *(bf16x8*)(sB + dstB[i]) = *(const bf16x8*)(srcB[i] + d0);
    __syncthreads();
    for (int j = 0; j < kk; ++j) {
      bf16x8 Bf[8];
      #pragma unroll
      for (int n = 0; n < 8; ++n) {
        int row = j * 128 + n * 16 + lrow;
        Bf[n] = *(const bf16x8*)(sB + row * 64 + ((lg ^ ((row >> 1) & 3)) << 4));
      }
      #pragma unroll
      for (int m = 0; m < 4; ++m) {
        int row = wv * 64 + m * 16 + lrow + j;   // shifted A read = conv shift
        bf16x8 Af = *(const bf16x8*)(sA + row * 64 + ((lg ^ ((row >> 1) & 3)) << 4));
        #pragma unroll
        for (int n = 0; n < 8; ++n)
          acc[m][n] = __builtin_amdgcn_mfma_f32_16x16x32_bf16(Af, Bf[n], acc[m][n], 0, 0, 0);
      }
    }
    __syncthreads();
  }

  // epilogue: per m-fragment single batch; bias + mask + relu + pool + atomic
  int rmv[4];
  #pragma unroll
  for (int m = 0; m < 4; ++m) rmv[m] = rowmap[P0 + wv * 64 + m * 16];
  #pragma unroll
  for (int n = 0; n < 8; ++n) {
    int fg = ff * 128 + n * 16 + lrow;       // f within branch [0,256)
    float bv = bias[fg];
    #pragma unroll
    for (int m = 0; m < 4; ++m) {
      int bb = rmv[m] >> 20;
      int Lb = (rmv[m] >> 10) & 1023;
      int t0 = (rmv[m] & 1023) + lg * 4;
      int vlim = Lb - kk + 1;
      float pmax = 0.f;
      #pragma unroll
      for (int i = 0; i < 4; ++i) {
        float v = acc[m][n][i] + bv;
        pmax = fmaxf(pmax, (t0 + i < vlim) ? fmaxf(v, 0.f) : 0.f);
      }
      pmax = fmaxf(pmax, __shfl_xor(pmax, 16));
      pmax = fmaxf(pmax, __shfl_xor(pmax, 32));
      if (lane < 16 && pmax > 0.f)
        atomicMax(feats + bb * 1024 + br * 256 + fg, __float_as_int(pmax));
    }
  }
}

// ---------------------------------------------------------------------------
// 4) FC + sigmoid
// ---------------------------------------------------------------------------
__global__ __launch_bounds__(64) void fc_kernel(
    const int* __restrict__ feats, const float* __restrict__ fcw,
    const float* __restrict__ fcb, float* __restrict__ out) {
  int b = blockIdx.x, lane = threadIdx.x;
  float acc = 0.f;
  for (int i = lane; i < 1024; i += 64)
    acc += __int_as_float(feats[b * 1024 + i]) * fcw[i];
  #pragma unroll
  for (int off = 32; off; off >>= 1) acc += __shfl_xor(acc, off);
  if (lane == 0) out[b] = 1.f / (1.f + expf(-(acc + fcb[0])));
}

extern "C" void kernel_launch(void* const* d_in, const int* in_sizes, int n_in,
                              void* d_out, int out_size, void* d_ws, size_t ws_size,
                              hipStream_t stream) {
  const int*   x   = (const int*)d_in[0];
  const float* h   = (const float*)d_in[1];
  const float* w2  = (const float*)d_in[2];
  const float* b2  = (const float*)d_in[3];
  const float* w3  = (const float*)d_in[4];
  const float* b3  = (const float*)d_in[5];
  const float* w4  = (const float*)d_in[6];
  const float* b4  = (const float*)d_in[7];
  const float* w5  = (const float*)d_in[8];
  const float* b5  = (const float*)d_in[9];
  const float* fcw = (const float*)d_in[10];
  const float* fcb = (const float*)d_in[11];
  float* out = (float*)d_out;
  char* ws = (char*)d_ws;
  unsigned short* hc = (unsigned short*)ws;               // 64*520*768*2 = 51,118,080
  unsigned short* Wp = (unsigned short*)(ws + 51118080);  // 3584*768*2   =  5,505,024
  int* feats  = (int*)(ws + 56623104);                    // 64*1024*4    =    262,144
  int* Lbuf   = (int*)(ws + 56885248);                    // 64*4
  int* plan   = (int*)(ws + 56885504);                    // 4 ints
  int* rowmap = (int*)(ws + 56885520);                    // (32768+260)*4 = 132,112

  hipMemsetAsync(feats, 0, 64 * 1024 * 4, stream);        // zero bits == 0.0f == relu floor
  compact_kernel<<<dim3(64, 8), 256, 0, stream>>>(x, h, hc, Lbuf);
  plan_kernel<<<1, 256, 0, stream>>>(Lbuf, plan, rowmap);
  wpack_kernel<<<3584, 128, 0, stream>>>(w2, w3, w4, w5, Wp);
  conv_kernel<<<1024, 256, 0, stream>>>(hc, Wp, b2, b3, b4, b5, plan, rowmap, feats);
  fc_kernel<<<64, 64, 0, stream>>>(feats, fcw, fcb, out);
}

// Round 4
// 169.365 us; speedup vs baseline: 1.5577x; 1.4643x over previous
//
#include <hip/hip_runtime.h>
#include <stdint.h>

#define Bn 64
#define Sn 512
#define SPn 520
#define Dn 768
#define Fn 256

typedef short bf16x8 __attribute__((ext_vector_type(8)));
typedef float f32x4 __attribute__((ext_vector_type(4)));

static __device__ __forceinline__ unsigned short f2bf(float f) {
  union { float f; unsigned u; } v; v.f = f;
  unsigned r = v.u + 0x7FFFu + ((v.u >> 16) & 1u);
  return (unsigned short)(r >> 16);
}

// async global->LDS, 16B per lane; LDS dest is wave-uniform base + lane*16
static __device__ __forceinline__ void gload16(const void* g, void* l) {
  __builtin_amdgcn_global_load_lds(
      (const __attribute__((address_space(1))) unsigned int*)g,
      (__attribute__((address_space(3))) unsigned int*)l, 16, 0, 0);
}

// ---------------------------------------------------------------------------
// 1) stable compaction + f32->bf16: hc[b][t][d], rows t>=L zeroed, 8 pad rows
// ---------------------------------------------------------------------------
__global__ __launch_bounds__(256) void compact_kernel(
    const int* __restrict__ x, const float* __restrict__ h,
    unsigned short* __restrict__ hc, int* __restrict__ Lout) {
  int b = blockIdx.x, rblk = blockIdx.y;
  __shared__ unsigned long long masks[8];
  __shared__ short sidx[Sn];
  int tid = threadIdx.x, lane = tid & 63, wv = tid >> 6;
  for (int c = wv; c < 8; c += 4) {
    bool pred = x[b * Sn + c * 64 + lane] != 0;
    unsigned long long m = __ballot(pred);
    if (lane == 0) masks[c] = m;
  }
  __syncthreads();
  int pref[9]; pref[0] = 0;
  #pragma unroll
  for (int c = 0; c < 8; ++c) pref[c + 1] = pref[c] + __popcll(masks[c]);
  int L = pref[8];
  for (int p = tid; p < Sn; p += 256) {
    int c = p >> 6, l = p & 63;
    unsigned long long m = masks[c];
    if ((m >> l) & 1ull)
      sidx[pref[c] + __popcll(m & ((1ull << l) - 1ull))] = (short)p;
  }
  if (rblk == 0 && tid == 0) Lout[b] = L;
  __syncthreads();
  int r0 = rblk * 65;  // 8 * 65 = 520 rows
  for (int r = r0 + wv; r < r0 + 65; r += 4) {
    unsigned short* dst = hc + ((size_t)b * SPn + r) * Dn;
    if (r < L) {
      const float* src = h + ((size_t)b * Sn + sidx[r]) * Dn;
      #pragma unroll
      for (int c = 0; c < 3; ++c) {
        int d = c * 256 + lane * 4;
        float4 v = *(const float4*)(src + d);
        ushort4 o = { f2bf(v.x), f2bf(v.y), f2bf(v.z), f2bf(v.w) };
        *(ushort4*)(dst + d) = o;
      }
    } else {
      ushort4 z = {0, 0, 0, 0};
      #pragma unroll
      for (int c = 0; c < 3; ++c) *(ushort4*)(dst + c * 256 + lane * 4) = z;
    }
  }
}

// ---------------------------------------------------------------------------
// 1.5) plan: 16-aligned per-batch segments packed densely; rowmap[p]=(b,L,t)
// ---------------------------------------------------------------------------
__global__ __launch_bounds__(256) void plan_kernel(
    const int* __restrict__ Lbuf, int* __restrict__ plan, int* __restrict__ rowmap) {
  __shared__ int sOff[65];
  __shared__ int sL[64];
  int tid = threadIdx.x;
  if (tid < 64) {
    int L = Lbuf[tid];
    int SL = (L + 15) & ~15;
    int pre = SL;
    #pragma unroll
    for (int off = 1; off < 64; off <<= 1) {
      int y = __shfl_up(pre, off);
      if (tid >= off) pre += y;
    }
    sOff[tid] = pre - SL;           // exclusive prefix
    sL[tid] = L;
    if (tid == 63) { sOff[64] = pre; plan[0] = (pre + 255) >> 8; }
  }
  __syncthreads();
  int M = sOff[64];
  for (int b = 0; b < 64; ++b) {
    int off = sOff[b], L = sL[b];
    int SL = (L + 15) & ~15;
    int enc = (b << 20) | (L << 10);
    for (int t = tid; t < SL; t += 256) rowmap[off + t] = enc | t;
  }
  for (int p = M + tid; p < M + 264; p += 256)
    rowmap[p] = 512;                // sentinel: b=0, L=0, t=512 (zero pad row)
}

// ---------------------------------------------------------------------------
// 2) weight repack: Wp[m][d] bf16, m = brOff + j*256 + f  (d innermost)
// ---------------------------------------------------------------------------
__global__ __launch_bounds__(128) void wpack_kernel(
    const float* __restrict__ w2, const float* __restrict__ w3,
    const float* __restrict__ w4, const float* __restrict__ w5,
    unsigned short* __restrict__ Wp) {
  int m = blockIdx.x;
  const float* w; int k, r;
  if (m < 512)       { w = w2; k = 2; r = m; }
  else if (m < 1280) { w = w3; k = 3; r = m - 512; }
  else if (m < 2304) { w = w4; k = 4; r = m - 1280; }
  else               { w = w5; k = 5; r = m - 2304; }
  int j = r >> 8, f = r & 255;
  const float* src = w + (size_t)f * Dn * k + j;   // w[f][d][j], stride k over d
  unsigned short* dst = Wp + (size_t)m * Dn;
  for (int d = threadIdx.x; d < Dn; d += 128) dst[d] = f2bf(src[(size_t)d * k]);
}

// ---------------------------------------------------------------------------
// 3) packed-M conv-GEMM with async global_load_lds + double-buffered LDS.
//    Steps over (d0, j): per step stage one tap's B (2 chunks/thr) into B-dbuf;
//    A staged once per d0 (5 chunks/thr) into A-dbuf. Swizzle via pre-swizzled
//    per-lane global source; LDS dest linear. One __syncthreads per step.
// ---------------------------------------------------------------------------
__global__ __launch_bounds__(256, 3) void conv_kernel(
    const unsigned short* __restrict__ hc, const unsigned short* __restrict__ Wp,
    const float* __restrict__ b2, const float* __restrict__ b3,
    const float* __restrict__ b4, const float* __restrict__ b5,
    const int* __restrict__ plan, const int* __restrict__ rowmap,
    int* __restrict__ feats) {
  __shared__ char smem[2 * 16896 + 2 * 8192];   // A dbuf 33792 + B dbuf 16384
  char* sA = smem;
  char* sB = smem + 33792;
  int idx = blockIdx.x;
  int sp = idx >> 7, tile = idx & 127;          // sub-major: heavy branches first
  if (tile >= plan[0]) return;
  int br = 3 - (sp >> 1), ff = sp & 1, kk = br + 2;
  int mBase = 256 * ((br * (br + 3)) >> 1) + ff * 128;  // 0,512,1280,2304 (+ff*128)
  const float* bias = (br == 0) ? b2 : (br == 1) ? b3 : (br == 2) ? b4 : b5;
  int tid = threadIdx.x, lane = tid & 63, wv = tid >> 6;
  int lrow = lane & 15, lg = lane >> 4;
  int P0 = tile << 8;
  int wvoff = wv * 1024;

  // per-lane pre-swizzled global sources (d0-invariant)
  const char* gA[4];
  #pragma unroll
  for (int p = 0; p < 4; ++p) {
    int c = p * 256 + tid;                      // chunk: row=c>>2, seg'=c&3
    int row = c >> 2, sgp = c & 3;
    int rm = rowmap[P0 + row];
    int bb_ = rm >> 20, t = rm & 1023;
    int seg = sgp ^ ((row >> 1) & 3);           // content that belongs at seg'
    gA[p] = (const char*)(hc + ((size_t)(bb_ * SPn + t)) * Dn + seg * 8);
  }
  const char* gAt;
  {
    int c = 992 + lane;                         // rows 248..263 (248-255 dup, benign)
    int row = c >> 2, sgp = c & 3;
    int rm = rowmap[P0 + row];
    int bb_ = rm >> 20, t = rm & 1023;
    int seg = sgp ^ ((row >> 1) & 3);
    gAt = (const char*)(hc + ((size_t)(bb_ * SPn + t)) * Dn + seg * 8);
  }
  const char* gB[2];
  #pragma unroll
  for (int q = 0; q < 2; ++q) {
    int c = q * 256 + tid;
    int row = c >> 2, sgp = c & 3;              // row in [0,128)
    int seg = sgp ^ ((row >> 1) & 3);
    gB[q] = (const char*)(Wp + ((size_t)(mBase + row)) * Dn + seg * 8);
  }

  f32x4 acc[4][8];
  #pragma unroll
  for (int m = 0; m < 4; ++m)
    #pragma unroll
    for (int n = 0; n < 8; ++n) acc[m][n] = (f32x4)0.f;

  // prologue: stage first A and first B
  {
    char* base = sA;
    #pragma unroll
    for (int p = 0; p < 4; ++p) gload16(gA[p], base + p * 4096 + wvoff);
    if (wv == 0) gload16(gAt, base + 15872);
    gload16(gB[0], sB + wvoff);
    gload16(gB[1], sB + 4096 + wvoff);
  }
  __syncthreads();

  int ab = 0, bbf = 0;
  for (int d0i = 0; d0i < 24; ++d0i) {
    const char* curA = sA + ab * 16896;
    for (int j = 0; j < kk; ++j) {
      // prefetch next step into the other buffers
      if (j + 1 < kk) {
        int off = (j + 1) * 393216 + d0i * 64;  // j*256 rows * 1536B + d0*64B
        char* base = sB + (bbf ^ 1) * 8192;
        gload16(gB[0] + off, base + wvoff);
        gload16(gB[1] + off, base + 4096 + wvoff);
      } else if (d0i + 1 < 24) {
        int off = (d0i + 1) * 64;
        char* baseB = sB + (bbf ^ 1) * 8192;
        gload16(gB[0] + off, baseB + wvoff);
        gload16(gB[1] + off, baseB + 4096 + wvoff);
        char* baseA = sA + (ab ^ 1) * 16896;
        #pragma unroll
        for (int p = 0; p < 4; ++p) gload16(gA[p] + off, baseA + p * 4096 + wvoff);
        if (wv == 0) gload16(gAt + off, baseA + 15872);
      }
      // compute current step
      const char* curB = sB + bbf * 8192;
      bf16x8 Af[4];
      #pragma unroll
      for (int m = 0; m < 4; ++m) {
        int row = wv * 64 + m * 16 + lrow + j;  // +j = the conv shift
        Af[m] = *(const bf16x8*)(curA + row * 64 + ((lg ^ ((row >> 1) & 3)) << 4));
      }
      #pragma unroll
      for (int n = 0; n < 8; ++n) {
        int row = n * 16 + lrow;
        bf16x8 Bf = *(const bf16x8*)(curB + row * 64 + ((lg ^ ((row >> 1) & 3)) << 4));
        #pragma unroll
        for (int m = 0; m < 4; ++m)
          acc[m][n] = __builtin_amdgcn_mfma_f32_16x16x32_bf16(Af[m], Bf, acc[m][n], 0, 0, 0);
      }
      __syncthreads();   // implicit vmcnt(0)+lgkmcnt(0): prefetched data landed
      bbf ^= 1;
    }
    ab ^= 1;
  }

  // epilogue: per m-fragment single batch; bias + mask + relu + pool + atomic
  int rmv[4];
  #pragma unroll
  for (int m = 0; m < 4; ++m) rmv[m] = rowmap[P0 + wv * 64 + m * 16];
  #pragma unroll
  for (int n = 0; n < 8; ++n) {
    int fg = ff * 128 + n * 16 + lrow;          // f within branch [0,256)
    float bv = bias[fg];
    #pragma unroll
    for (int m = 0; m < 4; ++m) {
      int bb_ = rmv[m] >> 20;
      int Lb = (rmv[m] >> 10) & 1023;
      int t0 = (rmv[m] & 1023) + lg * 4;
      int vlim = Lb - kk + 1;
      float pmax = 0.f;
      #pragma unroll
      for (int i = 0; i < 4; ++i) {
        float v = acc[m][n][i] + bv;
        pmax = fmaxf(pmax, (t0 + i < vlim) ? fmaxf(v, 0.f) : 0.f);
      }
      pmax = fmaxf(pmax, __shfl_xor(pmax, 16));
      pmax = fmaxf(pmax, __shfl_xor(pmax, 32));
      if (lane < 16 && pmax > 0.f)
        atomicMax(feats + bb_ * 1024 + br * 256 + fg, __float_as_int(pmax));
    }
  }
}

// ---------------------------------------------------------------------------
// 4) FC + sigmoid
// ---------------------------------------------------------------------------
__global__ __launch_bounds__(64) void fc_kernel(
    const int* __restrict__ feats, const float* __restrict__ fcw,
    const float* __restrict__ fcb, float* __restrict__ out) {
  int b = blockIdx.x, lane = threadIdx.x;
  float acc = 0.f;
  for (int i = lane; i < 1024; i += 64)
    acc += __int_as_float(feats[b * 1024 + i]) * fcw[i];
  #pragma unroll
  for (int off = 32; off; off >>= 1) acc += __shfl_xor(acc, off);
  if (lane == 0) out[b] = 1.f / (1.f + expf(-(acc + fcb[0])));
}

extern "C" void kernel_launch(void* const* d_in, const int* in_sizes, int n_in,
                              void* d_out, int out_size, void* d_ws, size_t ws_size,
                              hipStream_t stream) {
  const int*   x   = (const int*)d_in[0];
  const float* h   = (const float*)d_in[1];
  const float* w2  = (const float*)d_in[2];
  const float* b2  = (const float*)d_in[3];
  const float* w3  = (const float*)d_in[4];
  const float* b3  = (const float*)d_in[5];
  const float* w4  = (const float*)d_in[6];
  const float* b4  = (const float*)d_in[7];
  const float* w5  = (const float*)d_in[8];
  const float* b5  = (const float*)d_in[9];
  const float* fcw = (const float*)d_in[10];
  const float* fcb = (const float*)d_in[11];
  float* out = (float*)d_out;
  char* ws = (char*)d_ws;
  unsigned short* hc = (unsigned short*)ws;               // 64*520*768*2 = 51,118,080
  unsigned short* Wp = (unsigned short*)(ws + 51118080);  // 3584*768*2   =  5,505,024
  int* feats  = (int*)(ws + 56623104);                    // 64*1024*4    =    262,144
  int* Lbuf   = (int*)(ws + 56885248);                    // 64*4
  int* plan   = (int*)(ws + 56885504);                    // 4 ints
  int* rowmap = (int*)(ws + 56885520);                    // (32768+264)*4

  hipMemsetAsync(feats, 0, 64 * 1024 * 4, stream);        // zero bits == 0.0f == relu floor
  compact_kernel<<<dim3(64, 8), 256, 0, stream>>>(x, h, hc, Lbuf);
  plan_kernel<<<1, 256, 0, stream>>>(Lbuf, plan, rowmap);
  wpack_kernel<<<3584, 128, 0, stream>>>(w2, w3, w4, w5, Wp);
  conv_kernel<<<1024, 256, 0, stream>>>(hc, Wp, b2, b3, b4, b5, plan, rowmap, feats);
  fc_kernel<<<64, 64, 0, stream>>>(feats, fcw, fcb, out);
}

// Round 5
// 161.668 us; speedup vs baseline: 1.6318x; 1.0476x over previous
//
#include <hip/hip_runtime.h>
#include <stdint.h>

#define Bn 64
#define Sn 512
#define SPn 520
#define Dn 768
#define Fn 256
#define JSTRIDE 393216   // 256 rows * 1536 B : tap stride within Wp
#define ABUF 16640       // 260 rows * 64 B
#define BSLOT 8192       // 128 rows * 64 B

typedef short bf16x8 __attribute__((ext_vector_type(8)));
typedef float f32x4 __attribute__((ext_vector_type(4)));

static __device__ __forceinline__ unsigned short f2bf(float f) {
  union { float f; unsigned u; } v; v.f = f;
  unsigned r = v.u + 0x7FFFu + ((v.u >> 16) & 1u);
  return (unsigned short)(r >> 16);
}

// async global->LDS, 16B/lane; LDS dest = wave-uniform base + lane*16
static __device__ __forceinline__ void gload16(const void* g, void* l) {
  __builtin_amdgcn_global_load_lds(
      (const __attribute__((address_space(1))) unsigned int*)g,
      (__attribute__((address_space(3))) unsigned int*)l, 16, 0, 0);
}

template<int N> __device__ __forceinline__ void waitv() {
  static_assert(N == 0 || N == 2 || N == 7, "");
  if constexpr (N == 0) asm volatile("s_waitcnt vmcnt(0)" ::: "memory");
  else if constexpr (N == 2) asm volatile("s_waitcnt vmcnt(2)" ::: "memory");
  else asm volatile("s_waitcnt vmcnt(7)" ::: "memory");
}

// ---------------------------------------------------------------------------
// 1) stable compaction + f32->bf16: hc[b][t][d]; rows t>=L left stale
//    (stale rows feed only masked-out outputs; poison 0xAA = tiny finite bf16)
// ---------------------------------------------------------------------------
__global__ __launch_bounds__(256) void compact_kernel(
    const int* __restrict__ x, const float* __restrict__ h,
    unsigned short* __restrict__ hc, int* __restrict__ Lout) {
  int b = blockIdx.x, rblk = blockIdx.y;
  __shared__ unsigned long long masks[8];
  __shared__ short sidx[Sn];
  int tid = threadIdx.x, lane = tid & 63, wv = tid >> 6;
  for (int c = wv; c < 8; c += 4) {
    bool pred = x[b * Sn + c * 64 + lane] != 0;
    unsigned long long m = __ballot(pred);
    if (lane == 0) masks[c] = m;
  }
  __syncthreads();
  int pref[9]; pref[0] = 0;
  #pragma unroll
  for (int c = 0; c < 8; ++c) pref[c + 1] = pref[c] + __popcll(masks[c]);
  int L = pref[8];
  for (int p = tid; p < Sn; p += 256) {
    int c = p >> 6, l = p & 63;
    unsigned long long m = masks[c];
    if ((m >> l) & 1ull)
      sidx[pref[c] + __popcll(m & ((1ull << l) - 1ull))] = (short)p;
  }
  if (rblk == 0 && tid == 0) Lout[b] = L;
  __syncthreads();
  int r0 = rblk * 65;  // 8 * 65 = 520 rows
  for (int r = r0 + wv; r < r0 + 65; r += 4) {
    if (r < L) {
      unsigned short* dst = hc + ((size_t)b * SPn + r) * Dn;
      const float* src = h + ((size_t)b * Sn + sidx[r]) * Dn;
      #pragma unroll
      for (int c = 0; c < 3; ++c) {
        int d = c * 256 + lane * 4;
        float4 v = *(const float4*)(src + d);
        ushort4 o = { f2bf(v.x), f2bf(v.y), f2bf(v.z), f2bf(v.w) };
        *(ushort4*)(dst + d) = o;
      }
    }
  }
}

// ---------------------------------------------------------------------------
// 1.5) plan: 16-aligned per-batch segments packed densely; rowmap[p]=(b,L,t)
// ---------------------------------------------------------------------------
__global__ __launch_bounds__(256) void plan_kernel(
    const int* __restrict__ Lbuf, int* __restrict__ plan, int* __restrict__ rowmap) {
  __shared__ int sOff[65];
  __shared__ int sL[64];
  int tid = threadIdx.x;
  if (tid < 64) {
    int L = Lbuf[tid];
    int SL = (L + 15) & ~15;
    int pre = SL;
    #pragma unroll
    for (int off = 1; off < 64; off <<= 1) {
      int y = __shfl_up(pre, off);
      if (tid >= off) pre += y;
    }
    sOff[tid] = pre - SL;           // exclusive prefix
    sL[tid] = L;
    if (tid == 63) { sOff[64] = pre; plan[0] = (pre + 255) >> 8; }
  }
  __syncthreads();
  int M = sOff[64];
  for (int b = 0; b < 64; ++b) {
    int off = sOff[b], L = sL[b];
    int SL = (L + 15) & ~15;
    int enc = (b << 20) | (L << 10);
    for (int t = tid; t < SL; t += 256) rowmap[off + t] = enc | t;
  }
  for (int p = M + tid; p < M + 264; p += 256)
    rowmap[p] = 512;                // sentinel: b=0, L=0, t=512
}

// ---------------------------------------------------------------------------
// 2) weight repack via LDS bounce: coalesced reads AND writes
// ---------------------------------------------------------------------------
__global__ __launch_bounds__(256) void wpack_kernel(
    const float* __restrict__ w2, const float* __restrict__ w3,
    const float* __restrict__ w4, const float* __restrict__ w5,
    unsigned short* __restrict__ Wp) {
  __shared__ float sf[3840];        // up to 768*5
  int bb = blockIdx.x;
  int br = bb >> 8, f = bb & 255, k = br + 2;
  const float* w = (br == 0) ? w2 : (br == 1) ? w3 : (br == 2) ? w4 : w5;
  int mBase = 256 * ((br * (br + 3)) >> 1);
  const float* src = w + (size_t)f * Dn * k;
  int n = Dn * k;
  for (int e = threadIdx.x; e < n; e += 256) sf[e] = src[e];
  __syncthreads();
  for (int j = 0; j < k; ++j) {
    unsigned short* dst = Wp + (size_t)(mBase + j * 256 + f) * Dn;
    for (int d = threadIdx.x; d < Dn; d += 256) dst[d] = f2bf(sf[d * k + j]);
  }
}

// ---------------------------------------------------------------------------
// 3) packed-M conv-GEMM, counted-vmcnt pipeline (T3+T4+T5):
//    B taps write-ahead 2 into a 3-slot LDS ring; A 1 d0-tile ahead (dbuf).
//    One raw s_barrier per step; vmcnt never drains to 0 in the main loop.
// ---------------------------------------------------------------------------
template<int J, int W, int J2, int DADD, int DOA>
__device__ __forceinline__ void conv_step(
    int d0i, int bsl0, const char* curA, char* sA, char* sB,
    const char* const (&gA)[4], const char* gAt, const char* gB0, const char* gB1,
    int lane, int wv, int lrow, int lg, int wvoff, f32x4 (&acc)[4][8]) {
  int sl = bsl0 + J;           sl  -= (sl  >= 3) ? 3 : 0; sl  -= (sl  >= 3) ? 3 : 0;
  int dsl = bsl0 + J + 2;      dsl -= (dsl >= 3) ? 3 : 0; dsl -= (dsl >= 3) ? 3 : 0; dsl -= (dsl >= 3) ? 3 : 0;
  // stage issues (early): B(s+2), then A(d0i+1) at j==0
  {
    int boff = J2 * JSTRIDE + (d0i + DADD) * 64;
    gload16(gB0 + boff, sB + dsl * BSLOT + wvoff);
    gload16(gB1 + boff, sB + dsl * BSLOT + 4096 + wvoff);
  }
  if constexpr (DOA) {
    int aoff = (d0i + 1) * 64;
    char* nA = sA + ((d0i + 1) & 1) * ABUF;
    #pragma unroll
    for (int p = 0; p < 4; ++p) gload16(gA[p] + aoff, nA + p * 4096 + wvoff);
    if (lane < 16) gload16(gAt + aoff, nA + 16384);   // rows 256..259, exec-masked
  }
  // ds_read fragments for this step
  const char* curB = sB + sl * BSLOT;
  bf16x8 Af[4], Bf[8];
  #pragma unroll
  for (int m = 0; m < 4; ++m) {
    int row = wv * 64 + m * 16 + lrow + J;            // +J = the conv shift
    Af[m] = *(const bf16x8*)(curA + row * 64 + ((lg ^ ((row >> 1) & 3)) << 4));
  }
  #pragma unroll
  for (int n = 0; n < 8; ++n) {
    int row = n * 16 + lrow;
    Bf[n] = *(const bf16x8*)(curB + row * 64 + ((lg ^ ((row >> 1) & 3)) << 4));
  }
  __builtin_amdgcn_s_setprio(1);
  #pragma unroll
  for (int n = 0; n < 8; ++n)
    #pragma unroll
    for (int m = 0; m < 4; ++m)
      acc[m][n] = __builtin_amdgcn_mfma_f32_16x16x32_bf16(Af[m], Bf[n], acc[m][n], 0, 0, 0);
  __builtin_amdgcn_s_setprio(0);
  __builtin_amdgcn_sched_barrier(0);
  waitv<W>();                       // counted: own loads for next step landed
  __builtin_amdgcn_sched_barrier(0);
  __builtin_amdgcn_s_barrier();     // whole next slot now valid for all waves
  __builtin_amdgcn_sched_barrier(0);
}

template<int KK>
__device__ __forceinline__ void conv_loop(
    char* sA, char* sB, const char* const (&gA)[4], const char* gAt,
    const char* gB0, const char* gB1,
    int lane, int wv, int lrow, int lg, int wvoff, f32x4 (&acc)[4][8]) {
  // prologue: A(0); B(0)->slot0; B(1)->slot1
  #pragma unroll
  for (int p = 0; p < 4; ++p) gload16(gA[p], sA + p * 4096 + wvoff);
  if (lane < 16) gload16(gAt, sA + 16384);
  gload16(gB0, sB + wvoff);
  gload16(gB1, sB + 4096 + wvoff);
  gload16(gB0 + JSTRIDE, sB + BSLOT + wvoff);
  gload16(gB1 + JSTRIDE, sB + BSLOT + 4096 + wvoff);
  __builtin_amdgcn_sched_barrier(0);
  waitv<2>();                       // A(0)+B(0) landed; B(1) may fly
  __builtin_amdgcn_sched_barrier(0);
  __builtin_amdgcn_s_barrier();
  __builtin_amdgcn_sched_barrier(0);
  int bsl0 = 0;
  for (int d0i = 0; d0i < 24; ++d0i) {
    char* curA = sA + (d0i & 1) * ABUF;
    if constexpr (KK == 2) {
      conv_step<0,7,0,1,1>(d0i, bsl0, curA, sA, sB, gA, gAt, gB0, gB1, lane, wv, lrow, lg, wvoff, acc);
      conv_step<1,2,1,1,0>(d0i, bsl0, curA, sA, sB, gA, gAt, gB0, gB1, lane, wv, lrow, lg, wvoff, acc);
    } else if constexpr (KK == 3) {
      conv_step<0,7,2,0,1>(d0i, bsl0, curA, sA, sB, gA, gAt, gB0, gB1, lane, wv, lrow, lg, wvoff, acc);
      conv_step<1,7,0,1,0>(d0i, bsl0, curA, sA, sB, gA, gAt, gB0, gB1, lane, wv, lrow, lg, wvoff, acc);
      conv_step<2,2,1,1,0>(d0i, bsl0, curA, sA, sB, gA, gAt, gB0, gB1, lane, wv, lrow, lg, wvoff, acc);
    } else if constexpr (KK == 4) {
      conv_step<0,7,2,0,1>(d0i, bsl0, curA, sA, sB, gA, gAt, gB0, gB1, lane, wv, lrow, lg, wvoff, acc);
      conv_step<1,7,3,0,0>(d0i, bsl0, curA, sA, sB, gA, gAt, gB0, gB1, lane, wv, lrow, lg, wvoff, acc);
      conv_step<2,2,0,1,0>(d0i, bsl0, curA, sA, sB, gA, gAt, gB0, gB1, lane, wv, lrow, lg, wvoff, acc);
      conv_step<3,2,1,1,0>(d0i, bsl0, curA, sA, sB, gA, gAt, gB0, gB1, lane, wv, lrow, lg, wvoff, acc);
    } else {
      conv_step<0,7,2,0,1>(d0i, bsl0, curA, sA, sB, gA, gAt, gB0, gB1, lane, wv, lrow, lg, wvoff, acc);
      conv_step<1,7,3,0,0>(d0i, bsl0, curA, sA, sB, gA, gAt, gB0, gB1, lane, wv, lrow, lg, wvoff, acc);
      conv_step<2,2,4,0,0>(d0i, bsl0, curA, sA, sB, gA, gAt, gB0, gB1, lane, wv, lrow, lg, wvoff, acc);
      conv_step<3,2,0,1,0>(d0i, bsl0, curA, sA, sB, gA, gAt, gB0, gB1, lane, wv, lrow, lg, wvoff, acc);
      conv_step<4,2,1,1,0>(d0i, bsl0, curA, sA, sB, gA, gAt, gB0, gB1, lane, wv, lrow, lg, wvoff, acc);
    }
    bsl0 += KK; bsl0 -= (bsl0 >= 3) ? 3 : 0; bsl0 -= (bsl0 >= 3) ? 3 : 0;
  }
  waitv<0>();                       // no DMA may outlive this block's LDS
}

__global__ __launch_bounds__(256, 2) void conv_kernel(
    const unsigned short* __restrict__ hc, const unsigned short* __restrict__ Wp,
    const float* __restrict__ b2, const float* __restrict__ b3,
    const float* __restrict__ b4, const float* __restrict__ b5,
    const int* __restrict__ plan, const int* __restrict__ rowmap,
    int* __restrict__ feats) {
  __shared__ char smem[57856];      // A dbuf 2*16640 + B ring 3*8192
  char* sA = smem;
  char* sB = smem + 2 * ABUF;
  int idx = blockIdx.x;
  // XCD-aware decode: tile ≡ xcd (mod 8) so all 8 subs of a tile share an XCD
  int xcd = idx & 7, s2 = idx >> 3;
  int sub = s2 & 7, tile = xcd + ((s2 >> 3) << 3);
  if (tile >= plan[0]) return;
  int br = 3 - (sub >> 1), ff = sub & 1, kk = br + 2;
  int mBase = 256 * ((br * (br + 3)) >> 1) + ff * 128;
  const float* bias = (br == 0) ? b2 : (br == 1) ? b3 : (br == 2) ? b4 : b5;
  int tid = threadIdx.x, lane = tid & 63, wv = tid >> 6;
  int lrow = lane & 15, lg = lane >> 4;
  int wvoff = wv * 1024;
  int P0 = tile << 8;

  // per-lane pre-swizzled global sources (d0-invariant)
  const char* gA[4];
  #pragma unroll
  for (int p = 0; p < 4; ++p) {
    int c = p * 256 + tid;
    int row = c >> 2, sgp = c & 3;
    int rm = rowmap[P0 + row];
    int bb_ = rm >> 20, t = rm & 1023;
    int seg = sgp ^ ((row >> 1) & 3);
    gA[p] = (const char*)(hc + ((size_t)(bb_ * SPn + t)) * Dn + seg * 8);
  }
  const char* gAt;
  {
    int l = lane & 15;               // rows 256..259 (only lanes<16 used)
    int row = 256 + (l >> 2), sgp = l & 3;
    int rm = rowmap[P0 + row];
    int bb_ = rm >> 20, t = rm & 1023;
    int seg = sgp ^ ((row >> 1) & 3);
    gAt = (const char*)(hc + ((size_t)(bb_ * SPn + t)) * Dn + seg * 8);
  }
  const char* gB0;
  const char* gB1;
  {
    int row = tid >> 2, sgp = tid & 3;
    int seg = sgp ^ ((row >> 1) & 3);
    gB0 = (const char*)(Wp + ((size_t)(mBase + row)) * Dn + seg * 8);
    int c = 256 + tid;
    row = c >> 2; sgp = c & 3;
    seg = sgp ^ ((row >> 1) & 3);
    gB1 = (const char*)(Wp + ((size_t)(mBase + row)) * Dn + seg * 8);
  }

  f32x4 acc[4][8];
  #pragma unroll
  for (int m = 0; m < 4; ++m)
    #pragma unroll
    for (int n = 0; n < 8; ++n) acc[m][n] = (f32x4)0.f;

  switch (br) {
    case 3: conv_loop<5>(sA, sB, gA, gAt, gB0, gB1, lane, wv, lrow, lg, wvoff, acc); break;
    case 2: conv_loop<4>(sA, sB, gA, gAt, gB0, gB1, lane, wv, lrow, lg, wvoff, acc); break;
    case 1: conv_loop<3>(sA, sB, gA, gAt, gB0, gB1, lane, wv, lrow, lg, wvoff, acc); break;
    default: conv_loop<2>(sA, sB, gA, gAt, gB0, gB1, lane, wv, lrow, lg, wvoff, acc); break;
  }

  // epilogue: per m-fragment single batch; bias + mask + relu + pool + atomic
  int rmv[4];
  #pragma unroll
  for (int m = 0; m < 4; ++m) rmv[m] = rowmap[P0 + wv * 64 + m * 16];
  #pragma unroll
  for (int n = 0; n < 8; ++n) {
    int fg = ff * 128 + n * 16 + lrow;
    float bv = bias[fg];
    #pragma unroll
    for (int m = 0; m < 4; ++m) {
      int bb_ = rmv[m] >> 20;
      int Lb = (rmv[m] >> 10) & 1023;
      int t0 = (rmv[m] & 1023) + lg * 4;
      int vlim = Lb - kk + 1;
      float pmax = 0.f;
      #pragma unroll
      for (int i = 0; i < 4; ++i) {
        float v = acc[m][n][i] + bv;
        pmax = fmaxf(pmax, (t0 + i < vlim) ? fmaxf(v, 0.f) : 0.f);
      }
      pmax = fmaxf(pmax, __shfl_xor(pmax, 16));
      pmax = fmaxf(pmax, __shfl_xor(pmax, 32));
      if (lane < 16 && pmax > 0.f)
        atomicMax(feats + bb_ * 1024 + br * 256 + fg, __float_as_int(pmax));
    }
  }
}

// ---------------------------------------------------------------------------
// 4) FC + sigmoid
// ---------------------------------------------------------------------------
__global__ __launch_bounds__(64) void fc_kernel(
    const int* __restrict__ feats, const float* __restrict__ fcw,
    const float* __restrict__ fcb, float* __restrict__ out) {
  int b = blockIdx.x, lane = threadIdx.x;
  float acc = 0.f;
  for (int i = lane; i < 1024; i += 64)
    acc += __int_as_float(feats[b * 1024 + i]) * fcw[i];
  #pragma unroll
  for (int off = 32; off; off >>= 1) acc += __shfl_xor(acc, off);
  if (lane == 0) out[b] = 1.f / (1.f + expf(-(acc + fcb[0])));
}

extern "C" void kernel_launch(void* const* d_in, const int* in_sizes, int n_in,
                              void* d_out, int out_size, void* d_ws, size_t ws_size,
                              hipStream_t stream) {
  const int*   x   = (const int*)d_in[0];
  const float* h   = (const float*)d_in[1];
  const float* w2  = (const float*)d_in[2];
  const float* b2  = (const float*)d_in[3];
  const float* w3  = (const float*)d_in[4];
  const float* b3  = (const float*)d_in[5];
  const float* w4  = (const float*)d_in[6];
  const float* b4  = (const float*)d_in[7];
  const float* w5  = (const float*)d_in[8];
  const float* b5  = (const float*)d_in[9];
  const float* fcw = (const float*)d_in[10];
  const float* fcb = (const float*)d_in[11];
  float* out = (float*)d_out;
  char* ws = (char*)d_ws;
  unsigned short* hc = (unsigned short*)ws;               // 64*520*768*2 = 51,118,080
  unsigned short* Wp = (unsigned short*)(ws + 51118080);  // 3584*768*2   =  5,505,024
  int* feats  = (int*)(ws + 56623104);                    // 64*1024*4    =    262,144
  int* Lbuf   = (int*)(ws + 56885248);                    // 64*4
  int* plan   = (int*)(ws + 56885504);                    // 4 ints
  int* rowmap = (int*)(ws + 56885520);                    // (32768+264)*4

  hipMemsetAsync(feats, 0, 64 * 1024 * 4, stream);        // zero bits == 0.0f == relu floor
  compact_kernel<<<dim3(64, 8), 256, 0, stream>>>(x, h, hc, Lbuf);
  plan_kernel<<<1, 256, 0, stream>>>(Lbuf, plan, rowmap);
  wpack_kernel<<<1024, 256, 0, stream>>>(w2, w3, w4, w5, Wp);
  conv_kernel<<<1024, 256, 0, stream>>>(hc, Wp, b2, b3, b4, b5, plan, rowmap, feats);
  fc_kernel<<<64, 64, 0, stream>>>(feats, fcw, fcb, out);
}